// Round 1
// baseline (2228.495 us; speedup 1.0000x reference)
//
#include <hip/hip_runtime.h>
#include <hip/hip_bf16.h>
#include <cstddef>

// Problem constants (from reference):
//   K=2048, B=4, D=5, ATOM=125, BOND=12, HID=125, OUT=40
//   SIZES = [2048, 8192, 32768, 131072, 524288]
//   NOFF  = [0, 2048, 10240, 43008, 175104, 699392]
//   BOFF  = [0, 8192, 40960, 172032, 696320]
// Workspace layout (needs ~105 MB):
//   bufA: 524288*40 f32   (83.9 MB)
//   bufB: 131072*40 f32   (21.0 MB)
//   W2t : 40*125 f32      (20 KB)   -- W2 transposed

static constexpr int ATOM = 125, BOND = 12, HID = 125, OUT = 40;
static constexpr int IN_DIM = ATOM + BOND + OUT; // 177

__global__ void transpose_w2(const float* __restrict__ W2, float* __restrict__ W2t) {
    int idx = blockIdx.x * 64 + threadIdx.x;
    if (idx < HID * OUT) {
        int j = idx / OUT;   // 0..124
        int q = idx % OUT;   // 0..39
        W2t[q * HID + j] = W2[idx];
    }
}

__device__ __forceinline__ void fma_row(float h[HID], float xv, const float* __restrict__ wrow) {
#pragma unroll
    for (int j = 0; j < HID; ++j) h[j] = fmaf(xv, wrow[j], h[j]);
}

// One thread = one input row (one edge / one leaf).
// h[125] lives in VGPRs (all j-loops fully unrolled -> static indices).
// W1/W2t/b1/b2 addresses are wave-uniform -> scalar loads (s_load) expected.
template <bool LEAF>
__global__ void __launch_bounds__(64)
level_kernel(const float* __restrict__ msg,    // pre-offset, 125 per parent row
             const float* __restrict__ bond,   // pre-offset, 12 per row (unused if LEAF)
             const float* __restrict__ child,  // 40 per row (unused if LEAF)
             const float* __restrict__ W1,     // 177 x 125 row-major
             const float* __restrict__ b1,     // 125
             const float* __restrict__ W2t,    // 40 x 125 (transposed W2)
             const float* __restrict__ b2,     // 40
             float* __restrict__ out,          // LEAF: rows x 40 ; else (rows/4) x 40
             int rows) {
    int row = blockIdx.x * 64 + (int)threadIdx.x;
    if (row >= rows) return;  // rows is always a multiple of 64; never divergent

    float h[HID];
#pragma unroll
    for (int j = 0; j < HID; ++j) h[j] = b1[j];

    // ---- x @ W1 : msg part (125 features) ----
    const float* xm = msg + (size_t)(LEAF ? row : (row >> 2)) * ATOM;
#pragma unroll 1
    for (int k = 0; k < ATOM; ++k) fma_row(h, xm[k], W1 + (size_t)k * HID);

    if (!LEAF) {
        // ---- bond part (12 features) ----
        const float* xb = bond + (size_t)row * BOND;
#pragma unroll 1
        for (int k = 0; k < BOND; ++k) fma_row(h, xb[k], W1 + (size_t)(ATOM + k) * HID);
        // ---- child-output part (40 features) ----
        const float* xc = child + (size_t)row * OUT;
#pragma unroll 1
        for (int k = 0; k < OUT; ++k) fma_row(h, xc[k], W1 + (size_t)(ATOM + BOND + k) * HID);
    }

    // leaky_relu(h, 0.01): max(x, 0.01x) is exact for all signs
#pragma unroll
    for (int j = 0; j < HID; ++j) h[j] = fmaxf(h[j], 0.01f * h[j]);

    // ---- h @ W2 (+ leaky_relu) streamed per output column q; no o[] array ----
    float* orow = out + (size_t)(LEAF ? row : (row >> 2)) * OUT;
    const int sublane = (int)threadIdx.x & 3;
#pragma unroll 1
    for (int q = 0; q < OUT; ++q) {
        const float* wc = W2t + (size_t)q * HID;  // uniform -> s_load
        float a0 = 0.f, a1 = 0.f, a2 = 0.f, a3 = 0.f;
#pragma unroll
        for (int j = 0; j < HID - 1; j += 4) {
            a0 = fmaf(h[j + 0], wc[j + 0], a0);
            a1 = fmaf(h[j + 1], wc[j + 1], a1);
            a2 = fmaf(h[j + 2], wc[j + 2], a2);
            a3 = fmaf(h[j + 3], wc[j + 3], a3);
        }
        a0 = fmaf(h[HID - 1], wc[HID - 1], a0);
        float o = ((a0 + a1) + (a2 + a3)) + b2[q];
        o = fmaxf(o, 0.01f * o);
        if (LEAF) {
            orow[q] = o;
        } else {
            // sum over B=4 children = 4 consecutive lanes
            o += __shfl_xor(o, 1);
            o += __shfl_xor(o, 2);
            if (sublane == 0) orow[q] = o;
        }
    }
}

extern "C" void kernel_launch(void* const* d_in, const int* in_sizes, int n_in,
                              void* d_out, int out_size, void* d_ws, size_t ws_size,
                              hipStream_t stream) {
    const float* node_msg = (const float*)d_in[0];
    const float* bonds    = (const float*)d_in[1];
    const float* W1       = (const float*)d_in[2];
    const float* b1       = (const float*)d_in[3];
    const float* W2       = (const float*)d_in[4];
    const float* b2       = (const float*)d_in[5];
    float* out = (float*)d_out;

    // NOFF/BOFF constants
    const size_t NOFF0 = 0, NOFF1 = 2048, NOFF2 = 10240, NOFF3 = 43008, NOFF4 = 175104;
    const size_t BOFF0 = 0, BOFF1 = 8192, BOFF2 = 40960, BOFF3 = 172032;

    char* ws = (char*)d_ws;
    float* bufA = (float*)ws;                                     // 524288*40
    float* bufB = (float*)(ws + (size_t)524288 * 40 * 4);         // 131072*40
    float* W2t  = (float*)(ws + (size_t)524288 * 40 * 4 + (size_t)131072 * 40 * 4);

    transpose_w2<<<(HID * OUT + 63) / 64, 64, 0, stream>>>(W2, W2t);

    // Leaf level (d=4): 524288 rows, msg-only input, no B-sum
    level_kernel<true><<<524288 / 64, 64, 0, stream>>>(
        node_msg + NOFF4 * ATOM, nullptr, nullptr, W1, b1, W2t, b2, bufA, 524288);

    // d=3: 524288 edge rows -> 131072 parents
    level_kernel<false><<<524288 / 64, 64, 0, stream>>>(
        node_msg + NOFF3 * ATOM, bonds + BOFF3 * BOND, bufA, W1, b1, W2t, b2, bufB, 524288);

    // d=2: 131072 edge rows -> 32768 parents
    level_kernel<false><<<131072 / 64, 64, 0, stream>>>(
        node_msg + NOFF2 * ATOM, bonds + BOFF2 * BOND, bufB, W1, b1, W2t, b2, bufA, 131072);

    // d=1: 32768 edge rows -> 8192 parents
    level_kernel<false><<<32768 / 64, 64, 0, stream>>>(
        node_msg + NOFF1 * ATOM, bonds + BOFF1 * BOND, bufA, W1, b1, W2t, b2, bufB, 32768);

    // d=0: 8192 edge rows -> 2048 parents, final output
    level_kernel<false><<<8192 / 64, 64, 0, stream>>>(
        node_msg + NOFF0 * ATOM, bonds + BOFF0 * BOND, bufB, W1, b1, W2t, b2, out, 8192);
}

// Round 2
// 354.109 us; speedup vs baseline: 6.2933x; 6.2933x over previous
//
#include <hip/hip_runtime.h>
#include <hip/hip_bf16.h>
#include <cstddef>
#include <cstdint>

// K=2048, B=4, D=5, ATOM=125, BOND=12, HID=125, OUT=40
// NOFF = [0, 2048, 10240, 43008, 175104, 699392]
// BOFF = [0, 8192, 40960, 172032, 696320]
//
// Strategy: per level, rows = edges E. Layer1: H^T = W1t (A) @ X^T (B) via
// mfma_f32_16x16x32_bf16 with split-bf16 (hi/lo) on both operands (3 MFMAs).
// Acc layout => lane holds H for edge row (lane&15) at hids (lane>>4)*4+reg+16*mt,
// so layer2 (H @ W2) runs from registers with W2 pre-packed in matching
// fragment order (k-mapping is free as long as A and B agree). Layer2 D layout
// puts 4 consecutive edge rows in a lane's 4 regs -> B=4 parent sum is 3 adds.
// Intermediates stored bf16 (halves traffic; error ~1e-3 << 8.9e-2 threshold).

typedef __attribute__((ext_vector_type(8))) short short8;
typedef __attribute__((ext_vector_type(4))) float f32x4;
typedef __attribute__((ext_vector_type(4))) unsigned int v4u;
typedef __attribute__((ext_vector_type(2))) unsigned int v2u;

static constexpr int ATOM = 125, BOND = 12, HID = 125, OUT = 40;

__device__ __forceinline__ unsigned short f2bf(float x) {
    __hip_bfloat16 b = __float2bfloat16(x);  // RNE
    return __builtin_bit_cast(unsigned short, b);
}
__device__ __forceinline__ float bf_residual(float x, unsigned short h) {
    __hip_bfloat16 b = __builtin_bit_cast(__hip_bfloat16, h);
    return x - __bfloat162float(b);
}
__device__ __forceinline__ unsigned int pack2(unsigned short a, unsigned short b) {
    return (unsigned int)a | ((unsigned int)b << 16);
}

// W1t hi/lo: [128 hid][192 k] bf16, zero-padded (hid>=125 or k>=177 -> 0)
__global__ void prep_w1(const float* __restrict__ W1,
                        unsigned short* __restrict__ w1h,
                        unsigned short* __restrict__ w1l) {
    int idx = blockIdx.x * 256 + threadIdx.x;
    if (idx >= 128 * 192) return;
    int hid = idx / 192, k = idx % 192;
    float v = (hid < HID && k < ATOM + BOND + OUT) ? W1[(size_t)k * HID + hid] : 0.f;
    unsigned short h = f2bf(v);
    unsigned short l = f2bf(bf_residual(v, h));
    w1h[idx] = h;
    w1l[idx] = l;
}

// W2 pre-packed in layer2 B-fragment order (plain bf16):
// frag fr = kt*3+qt; lane ln; elem j: hid = kt*32 + 16*(j>>2) + (ln>>4)*4 + (j&3),
// q = qt*16 + (ln&15). Stored as 4 u32 per (fr,lane).
__global__ void prep_w2(const float* __restrict__ W2, unsigned int* __restrict__ w2f) {
    int t = threadIdx.x;
    for (int task = t; task < 12 * 64; task += 256) {
        int ln = task & 63, fr = task >> 6;
        int kt = fr / 3, qt = fr % 3;
        int q = qt * 16 + (ln & 15);
        unsigned int w[4];
#pragma unroll
        for (int jp = 0; jp < 4; jp++) {
            unsigned short e[2];
#pragma unroll
            for (int s = 0; s < 2; s++) {
                int j = jp * 2 + s;
                int hid = kt * 32 + ((j >> 2) << 4) + ((ln >> 4) << 2) + (j & 3);
                float v = (hid < HID && q < OUT) ? W2[(size_t)hid * OUT + q] : 0.f;
                e[s] = f2bf(v);
            }
            w[jp] = pack2(e[0], e[1]);
        }
        v4u val = {w[0], w[1], w[2], w[3]};
        ((v4u*)w2f)[fr * 64 + ln] = val;
    }
}

// Block: 256 threads = 4 waves; 256 edge rows/block; wave tile = 128 hid x 64 rows.
template <bool LEAF, bool FINAL>
__global__ void __launch_bounds__(256, 2)
level_mlp(const float* __restrict__ msg,
          const float* __restrict__ bond,
          const __hip_bfloat16* __restrict__ child,
          const unsigned short* __restrict__ w1h,
          const unsigned short* __restrict__ w1l,
          const unsigned int* __restrict__ w2f,
          const float* __restrict__ b1,
          const float* __restrict__ b2,
          void* __restrict__ outp) {
    constexpr int NC = LEAF ? 4 : 6;  // K chunks of 32 (leaf: 125 feats, else 177)

    __shared__ __align__(16) unsigned short Xh[256 * 40];  // [row][k+pad], 80B stride
    __shared__ __align__(16) unsigned short Xl[256 * 40];
    __shared__ __align__(16) unsigned short Wh[128 * 40];
    __shared__ __align__(16) unsigned short Wl[128 * 40];

    const int tid = threadIdx.x;
    const int lane = tid & 63;
    const int wv = tid >> 6;
    const int l15 = tid & 15;
    const int l16 = (tid >> 4) & 3;
    const int base = blockIdx.x * 256;

    // acc init = b1 (hid pad -> 0); h = X@W1 + b1 accumulates on top
    f32x4 acc[8][4];
#pragma unroll
    for (int mt = 0; mt < 8; mt++) {
        f32x4 bi;
#pragma unroll
        for (int r = 0; r < 4; r++) {
            int hid = mt * 16 + l16 * 4 + r;
            bi[r] = (hid < HID) ? b1[hid] : 0.f;
        }
#pragma unroll
        for (int nt = 0; nt < 4; nt++) acc[mt][nt] = bi;
    }

    // X prefetch registers: thread stages rows (tid>>3)+32p, feats fg..fg+3
    float xr[4][8];
    const int fg = (tid & 7) * 4;
    const int rb = tid >> 3;

    auto load_x = [&](int kc) {
#pragma unroll
        for (int i = 0; i < 4; i++) {
            int f = kc * 32 + fg + i;
            if (f < ATOM) {
#pragma unroll
                for (int p = 0; p < 8; p++) {
                    int row = base + rb + 32 * p;
                    int mr = LEAF ? row : (row >> 2);
                    xr[i][p] = msg[(size_t)mr * ATOM + f];
                }
            } else if (!LEAF && f < ATOM + BOND) {
#pragma unroll
                for (int p = 0; p < 8; p++) {
                    int row = base + rb + 32 * p;
                    xr[i][p] = bond[(size_t)row * BOND + (f - ATOM)];
                }
            } else if (!LEAF && f < ATOM + BOND + OUT) {
#pragma unroll
                for (int p = 0; p < 8; p++) {
                    int row = base + rb + 32 * p;
                    xr[i][p] = __bfloat162float(child[(size_t)row * OUT + (f - ATOM - BOND)]);
                }
            } else {
#pragma unroll
                for (int p = 0; p < 8; p++) xr[i][p] = 0.f;
            }
        }
    };

    load_x(0);

#pragma unroll 1
    for (int kc = 0; kc < NC; ++kc) {
        if (kc) __syncthreads();
        // ---- stage W1t chunk (ws -> LDS), hi+lo ----
        {
            int r = tid >> 1, half = tid & 1;
            const v4u* sh = (const v4u*)(w1h + (size_t)r * 192 + kc * 32 + half * 16);
            const v4u* sl = (const v4u*)(w1l + (size_t)r * 192 + kc * 32 + half * 16);
            v4u a0 = sh[0], a1 = sh[1];
            v4u c0 = sl[0], c1 = sl[1];
            *(v4u*)&Wh[r * 40 + half * 16] = a0;
            *(v4u*)&Wh[r * 40 + half * 16 + 8] = a1;
            *(v4u*)&Wl[r * 40 + half * 16] = c0;
            *(v4u*)&Wl[r * 40 + half * 16 + 8] = c1;
        }
        // ---- stage X chunk from prefetch regs (cvt to hi/lo bf16) ----
#pragma unroll
        for (int p = 0; p < 8; p++) {
            int rl = rb + 32 * p;
            unsigned short h0 = f2bf(xr[0][p]), h1 = f2bf(xr[1][p]);
            unsigned short h2 = f2bf(xr[2][p]), h3 = f2bf(xr[3][p]);
            unsigned short q0 = f2bf(bf_residual(xr[0][p], h0));
            unsigned short q1 = f2bf(bf_residual(xr[1][p], h1));
            unsigned short q2 = f2bf(bf_residual(xr[2][p], h2));
            unsigned short q3 = f2bf(bf_residual(xr[3][p], h3));
            v2u hv = {pack2(h0, h1), pack2(h2, h3)};
            v2u lv = {pack2(q0, q1), pack2(q2, q3)};
            *(v2u*)&Xh[rl * 40 + fg] = hv;
            *(v2u*)&Xl[rl * 40 + fg] = lv;
        }
        // issue next chunk's global loads (overlap with MFMA below)
        if (kc + 1 < NC) load_x(kc + 1);
        __syncthreads();

        // ---- MFMA phase: A = W1t frags, B = X frags, 3-way split ----
        short8 xh[4], xl[4];
#pragma unroll
        for (int nt = 0; nt < 4; nt++) {
            int r = wv * 64 + nt * 16 + l15;
            xh[nt] = *(const short8*)&Xh[r * 40 + l16 * 8];
            xl[nt] = *(const short8*)&Xl[r * 40 + l16 * 8];
        }
#pragma unroll
        for (int mt = 0; mt < 8; mt++) {
            int hr = mt * 16 + l15;
            short8 wh_ = *(const short8*)&Wh[hr * 40 + l16 * 8];
            short8 wl_ = *(const short8*)&Wl[hr * 40 + l16 * 8];
#pragma unroll
            for (int nt = 0; nt < 4; nt++) {
                acc[mt][nt] = __builtin_amdgcn_mfma_f32_16x16x32_bf16(wh_, xh[nt], acc[mt][nt], 0, 0, 0);
                acc[mt][nt] = __builtin_amdgcn_mfma_f32_16x16x32_bf16(wh_, xl[nt], acc[mt][nt], 0, 0, 0);
                acc[mt][nt] = __builtin_amdgcn_mfma_f32_16x16x32_bf16(wl_, xh[nt], acc[mt][nt], 0, 0, 0);
            }
        }
    }

    // leaky_relu on h (exact: max(x, 0.01x))
#pragma unroll
    for (int mt = 0; mt < 8; mt++)
#pragma unroll
        for (int nt = 0; nt < 4; nt++)
#pragma unroll
            for (int r = 0; r < 4; r++)
                acc[mt][nt][r] = fmaxf(acc[mt][nt][r], 0.01f * acc[mt][nt][r]);

    // ---- layer 2: o = lrelu(h @ W2 + b2), all from registers ----
    v4u wf[4][3];
#pragma unroll
    for (int kt = 0; kt < 4; kt++)
#pragma unroll
        for (int qt = 0; qt < 3; qt++)
            wf[kt][qt] = *(const v4u*)&w2f[((kt * 3 + qt) * 64 + lane) * 4];
    float b2v[3];
#pragma unroll
    for (int qt = 0; qt < 3; qt++) {
        int q = qt * 16 + l15;
        b2v[qt] = (q < OUT) ? b2[q] : 0.f;
    }

#pragma unroll
    for (int nt = 0; nt < 4; nt++) {
        // A-frags from acc (plain bf16), k-mapping matches prep_w2
        short8 A[4];
#pragma unroll
        for (int kt = 0; kt < 4; kt++) {
            unsigned int u0 = pack2(f2bf(acc[2 * kt][nt][0]), f2bf(acc[2 * kt][nt][1]));
            unsigned int u1 = pack2(f2bf(acc[2 * kt][nt][2]), f2bf(acc[2 * kt][nt][3]));
            unsigned int u2 = pack2(f2bf(acc[2 * kt + 1][nt][0]), f2bf(acc[2 * kt + 1][nt][1]));
            unsigned int u3 = pack2(f2bf(acc[2 * kt + 1][nt][2]), f2bf(acc[2 * kt + 1][nt][3]));
            v4u av = {u0, u1, u2, u3};
            A[kt] = __builtin_bit_cast(short8, av);
        }
        f32x4 o[3];
#pragma unroll
        for (int qt = 0; qt < 3; qt++) {
            f32x4 z = {0.f, 0.f, 0.f, 0.f};
            o[qt] = z;
        }
#pragma unroll
        for (int qt = 0; qt < 3; qt++)
#pragma unroll
            for (int kt = 0; kt < 4; kt++)
                o[qt] = __builtin_amdgcn_mfma_f32_16x16x32_bf16(
                    A[kt], __builtin_bit_cast(short8, wf[kt][qt]), o[qt], 0, 0, 0);

        // epilogue: rows = base + wv*64 + nt*16 + l16*4 + r ; q = qt*16 + l15
        if (LEAF) {
            __hip_bfloat16* ob = (__hip_bfloat16*)outp;
#pragma unroll
            for (int qt = 0; qt < 3; qt++) {
                int q = qt * 16 + l15;
                if (q < OUT) {
#pragma unroll
                    for (int r = 0; r < 4; r++) {
                        int row = base + wv * 64 + nt * 16 + l16 * 4 + r;
                        float v = o[qt][r] + b2v[qt];
                        v = fmaxf(v, 0.01f * v);
                        ob[(size_t)row * OUT + q] = __float2bfloat16(v);
                    }
                }
            }
        } else {
            // lrelu per edge row FIRST, then sum the 4 children (one lane's 4 regs)
#pragma unroll
            for (int qt = 0; qt < 3; qt++) {
                int q = qt * 16 + l15;
                float s = 0.f;
#pragma unroll
                for (int r = 0; r < 4; r++) {
                    float v = o[qt][r] + b2v[qt];
                    s += fmaxf(v, 0.01f * v);
                }
                if (q < OUT) {
                    int p = (base >> 2) + wv * 16 + nt * 4 + l16;
                    if (FINAL)
                        ((float*)outp)[(size_t)p * OUT + q] = s;
                    else
                        ((__hip_bfloat16*)outp)[(size_t)p * OUT + q] = __float2bfloat16(s);
                }
            }
        }
    }
}

extern "C" void kernel_launch(void* const* d_in, const int* in_sizes, int n_in,
                              void* d_out, int out_size, void* d_ws, size_t ws_size,
                              hipStream_t stream) {
    const float* node_msg = (const float*)d_in[0];
    const float* bonds = (const float*)d_in[1];
    const float* W1 = (const float*)d_in[2];
    const float* b1 = (const float*)d_in[3];
    const float* W2 = (const float*)d_in[4];
    const float* b2 = (const float*)d_in[5];
    float* out = (float*)d_out;

    char* ws = (char*)d_ws;
    __hip_bfloat16* bufA = (__hip_bfloat16*)ws;                           // 524288*40 bf16 = 41943040 B
    __hip_bfloat16* bufB = (__hip_bfloat16*)(ws + 41943040);              // 131072*40 bf16 = 10485760 B
    unsigned short* w1h = (unsigned short*)(ws + 52428800);               // 128*192*2 = 49152 B
    unsigned short* w1l = (unsigned short*)(ws + 52428800 + 49152);       // 49152 B
    unsigned int* w2f = (unsigned int*)(ws + 52428800 + 98304);           // 12*64*16 = 12288 B

    prep_w1<<<96, 256, 0, stream>>>(W1, w1h, w1l);
    prep_w2<<<1, 256, 0, stream>>>(W2, w2f);

    // d=4 (leaf): 524288 rows, msg only, no sum, out bf16
    level_mlp<true, false><<<2048, 256, 0, stream>>>(
        node_msg + (size_t)175104 * ATOM, nullptr, nullptr, w1h, w1l, w2f, b1, b2, bufA);
    // d=3: 524288 edges -> 131072 parents
    level_mlp<false, false><<<2048, 256, 0, stream>>>(
        node_msg + (size_t)43008 * ATOM, bonds + (size_t)172032 * BOND, bufA,
        w1h, w1l, w2f, b1, b2, bufB);
    // d=2: 131072 edges -> 32768 parents
    level_mlp<false, false><<<512, 256, 0, stream>>>(
        node_msg + (size_t)10240 * ATOM, bonds + (size_t)40960 * BOND, bufB,
        w1h, w1l, w2f, b1, b2, bufA);
    // d=1: 32768 edges -> 8192 parents
    level_mlp<false, false><<<128, 256, 0, stream>>>(
        node_msg + (size_t)2048 * ATOM, bonds + (size_t)8192 * BOND, bufA,
        w1h, w1l, w2f, b1, b2, bufB);
    // d=0: 8192 edges -> 2048 parents, final fp32 output
    level_mlp<false, true><<<32, 256, 0, stream>>>(
        node_msg, bonds, bufB, w1h, w1l, w2f, b1, b2, out);
}

// Round 3
// 310.419 us; speedup vs baseline: 7.1790x; 1.1407x over previous
//
#include <hip/hip_runtime.h>
#include <hip/hip_bf16.h>
#include <cstddef>
#include <cstdint>

// K=2048, B=4, D=5, ATOM=125, BOND=12, HID=125, OUT=40
// NOFF = [0, 2048, 10240, 43008, 175104, 699392]
// BOFF = [0, 8192, 40960, 172032, 696320]
//
// Layer1: H^T = (W1hi + W1lo) @ X  via 2x mfma_f32_16x16x32_bf16 (W split
// hi/lo for fp32-grade weight precision; X plain bf16 -- validated margin).
// Acc: lane holds H of edge row (lane&15) at hid (lane>>4)*4+reg+16*mt.
// Layer2 runs entirely from registers with W2 pre-packed in fragment order.
// Layer2 D layout puts 4 consecutive edge rows in one lane's 4 acc regs ->
// B=4 parent sum is 3 adds. Intermediates bf16.
// Block = 256 thr / 4 waves; 128 rows/block; wave tile = 128 hid x 32 rows.
// LDS 30 KB, acc 64 VGPR -> ~3 blocks/CU.

typedef __attribute__((ext_vector_type(8))) short short8;
typedef __attribute__((ext_vector_type(4))) float f32x4;
typedef __attribute__((ext_vector_type(4))) unsigned int v4u;
typedef __attribute__((ext_vector_type(2))) unsigned int v2u;

static constexpr int ATOM = 125, BOND = 12, HID = 125, OUT = 40;

__device__ __forceinline__ unsigned short f2bf(float x) {
    __hip_bfloat16 b = __float2bfloat16(x);  // RNE
    return __builtin_bit_cast(unsigned short, b);
}
__device__ __forceinline__ float bf_residual(float x, unsigned short h) {
    __hip_bfloat16 b = __builtin_bit_cast(__hip_bfloat16, h);
    return x - __bfloat162float(b);
}
__device__ __forceinline__ unsigned int pack2(unsigned short a, unsigned short b) {
    return (unsigned int)a | ((unsigned int)b << 16);
}

// W1t hi/lo: [128 hid][192 k] bf16, zero-padded (hid>=125 or k>=177 -> 0)
__global__ void prep_w1(const float* __restrict__ W1,
                        unsigned short* __restrict__ w1h,
                        unsigned short* __restrict__ w1l) {
    int idx = blockIdx.x * 256 + threadIdx.x;
    if (idx >= 128 * 192) return;
    int hid = idx / 192, k = idx % 192;
    float v = (hid < HID && k < ATOM + BOND + OUT) ? W1[(size_t)k * HID + hid] : 0.f;
    unsigned short h = f2bf(v);
    unsigned short l = f2bf(bf_residual(v, h));
    w1h[idx] = h;
    w1l[idx] = l;
}

// W2 pre-packed in layer2 B-fragment order (plain bf16):
// frag fr = kt*3+qt; lane ln; elem j: hid = kt*32 + 16*(j>>2) + (ln>>4)*4 + (j&3),
// q = qt*16 + (ln&15). Stored as 4 u32 per (fr,lane).
__global__ void prep_w2(const float* __restrict__ W2, unsigned int* __restrict__ w2f) {
    int t = threadIdx.x;
    for (int task = t; task < 12 * 64; task += 256) {
        int ln = task & 63, fr = task >> 6;
        int kt = fr / 3, qt = fr % 3;
        int q = qt * 16 + (ln & 15);
        unsigned int w[4];
#pragma unroll
        for (int jp = 0; jp < 4; jp++) {
            unsigned short e[2];
#pragma unroll
            for (int s = 0; s < 2; s++) {
                int j = jp * 2 + s;
                int hid = kt * 32 + ((j >> 2) << 4) + ((ln >> 4) << 2) + (j & 3);
                float v = (hid < HID && q < OUT) ? W2[(size_t)hid * OUT + q] : 0.f;
                e[s] = f2bf(v);
            }
            w[jp] = pack2(e[0], e[1]);
        }
        v4u val = {w[0], w[1], w[2], w[3]};
        ((v4u*)w2f)[fr * 64 + ln] = val;
    }
}

template <bool LEAF, bool FINAL>
__global__ void __launch_bounds__(256, 2)
level_mlp(const float* __restrict__ msg,
          const float* __restrict__ bond,
          const __hip_bfloat16* __restrict__ child,
          const unsigned short* __restrict__ w1h,
          const unsigned short* __restrict__ w1l,
          const unsigned int* __restrict__ w2f,
          const float* __restrict__ b1,
          const float* __restrict__ b2,
          void* __restrict__ outp) {
    constexpr int NC = LEAF ? 4 : 6;  // K chunks of 32 (leaf: 125 feats, else 177)

    __shared__ __align__(16) unsigned short Xh[128 * 40];  // [row][k], 80B stride
    __shared__ __align__(16) unsigned short Wh[128 * 40];
    __shared__ __align__(16) unsigned short Wl[128 * 40];

    const int tid = threadIdx.x;
    const int wv = tid >> 6;
    const int l15 = tid & 15;
    const int l16 = (tid >> 4) & 3;
    const int base = blockIdx.x * 128;

    // acc init = b1 (hid pad -> 0)
    f32x4 acc[8][2];
#pragma unroll
    for (int mt = 0; mt < 8; mt++) {
        f32x4 bi;
#pragma unroll
        for (int r = 0; r < 4; r++) {
            int hid = mt * 16 + l16 * 4 + r;
            bi[r] = (hid < HID) ? b1[hid] : 0.f;
        }
#pragma unroll
        for (int nt = 0; nt < 2; nt++) acc[mt][nt] = bi;
    }

    // X prefetch regs: thread stages rows rb+32p (p<4), feats fg..fg+3
    float xr[4][4];
    const int fg = (tid & 7) * 4;
    const int rb = tid >> 3;

    auto load_x = [&](int kc) {
#pragma unroll
        for (int i = 0; i < 4; i++) {
            int f = kc * 32 + fg + i;
            if (f < ATOM) {
#pragma unroll
                for (int p = 0; p < 4; p++) {
                    int row = base + rb + 32 * p;
                    int mr = LEAF ? row : (row >> 2);
                    xr[i][p] = msg[(size_t)mr * ATOM + f];
                }
            } else if (!LEAF && f < ATOM + BOND) {
#pragma unroll
                for (int p = 0; p < 4; p++) {
                    int row = base + rb + 32 * p;
                    xr[i][p] = bond[(size_t)row * BOND + (f - ATOM)];
                }
            } else if (!LEAF && f < ATOM + BOND + OUT) {
#pragma unroll
                for (int p = 0; p < 4; p++) {
                    int row = base + rb + 32 * p;
                    xr[i][p] = __bfloat162float(child[(size_t)row * OUT + (f - ATOM - BOND)]);
                }
            } else {
#pragma unroll
                for (int p = 0; p < 4; p++) xr[i][p] = 0.f;
            }
        }
    };

    load_x(0);

#pragma unroll 1
    for (int kc = 0; kc < NC; ++kc) {
        if (kc) __syncthreads();
        // ---- stage W1t chunk (hi+lo) ----
        {
            int r = tid >> 1, half = tid & 1;
            const v4u* sh = (const v4u*)(w1h + (size_t)r * 192 + kc * 32 + half * 16);
            const v4u* sl = (const v4u*)(w1l + (size_t)r * 192 + kc * 32 + half * 16);
            v4u a0 = sh[0], a1 = sh[1];
            v4u c0 = sl[0], c1 = sl[1];
            *(v4u*)&Wh[r * 40 + half * 16] = a0;
            *(v4u*)&Wh[r * 40 + half * 16 + 8] = a1;
            *(v4u*)&Wl[r * 40 + half * 16] = c0;
            *(v4u*)&Wl[r * 40 + half * 16 + 8] = c1;
        }
        // ---- stage X chunk from prefetch regs (plain bf16) ----
#pragma unroll
        for (int p = 0; p < 4; p++) {
            int rl = rb + 32 * p;
            v2u hv = {pack2(f2bf(xr[0][p]), f2bf(xr[1][p])),
                      pack2(f2bf(xr[2][p]), f2bf(xr[3][p]))};
            *(v2u*)&Xh[rl * 40 + fg] = hv;
        }
        if (kc + 1 < NC) load_x(kc + 1);  // overlap next chunk's loads with MFMA
        __syncthreads();

        // ---- MFMA: A = W1t (hi then lo), B = X ----
        short8 xh[2];
#pragma unroll
        for (int nt = 0; nt < 2; nt++) {
            int r = wv * 32 + nt * 16 + l15;
            xh[nt] = *(const short8*)&Xh[r * 40 + l16 * 8];
        }
#pragma unroll
        for (int mt = 0; mt < 8; mt++) {
            int hr = mt * 16 + l15;
            short8 wh_ = *(const short8*)&Wh[hr * 40 + l16 * 8];
            short8 wl_ = *(const short8*)&Wl[hr * 40 + l16 * 8];
#pragma unroll
            for (int nt = 0; nt < 2; nt++) {
                acc[mt][nt] = __builtin_amdgcn_mfma_f32_16x16x32_bf16(wh_, xh[nt], acc[mt][nt], 0, 0, 0);
                acc[mt][nt] = __builtin_amdgcn_mfma_f32_16x16x32_bf16(wl_, xh[nt], acc[mt][nt], 0, 0, 0);
            }
        }
    }

    // leaky_relu on h (exact: max(x, 0.01x))
#pragma unroll
    for (int mt = 0; mt < 8; mt++)
#pragma unroll
        for (int nt = 0; nt < 2; nt++)
#pragma unroll
            for (int r = 0; r < 4; r++)
                acc[mt][nt][r] = fmaxf(acc[mt][nt][r], 0.01f * acc[mt][nt][r]);

    // ---- layer 2: o = lrelu(h @ W2 + b2), from registers ----
    float b2v[3];
#pragma unroll
    for (int qt = 0; qt < 3; qt++) {
        int q = qt * 16 + l15;
        b2v[qt] = (q < OUT) ? b2[q] : 0.f;
    }
    const int lane = tid & 63;

#pragma unroll
    for (int nt = 0; nt < 2; nt++) {
        short8 A[4];
#pragma unroll
        for (int kt = 0; kt < 4; kt++) {
            unsigned int u0 = pack2(f2bf(acc[2 * kt][nt][0]), f2bf(acc[2 * kt][nt][1]));
            unsigned int u1 = pack2(f2bf(acc[2 * kt][nt][2]), f2bf(acc[2 * kt][nt][3]));
            unsigned int u2 = pack2(f2bf(acc[2 * kt + 1][nt][0]), f2bf(acc[2 * kt + 1][nt][1]));
            unsigned int u3 = pack2(f2bf(acc[2 * kt + 1][nt][2]), f2bf(acc[2 * kt + 1][nt][3]));
            v4u av = {u0, u1, u2, u3};
            A[kt] = __builtin_bit_cast(short8, av);
        }
#pragma unroll
        for (int qt = 0; qt < 3; qt++) {
            f32x4 o = {0.f, 0.f, 0.f, 0.f};
#pragma unroll
            for (int kt = 0; kt < 4; kt++) {
                v4u wv_ = *(const v4u*)&w2f[((kt * 3 + qt) * 64 + lane) * 4];  // L2-hot
                o = __builtin_amdgcn_mfma_f32_16x16x32_bf16(
                    A[kt], __builtin_bit_cast(short8, wv_), o, 0, 0, 0);
            }
            int q = qt * 16 + l15;
            if (LEAF) {
                __hip_bfloat16* ob = (__hip_bfloat16*)outp;
                if (q < OUT) {
#pragma unroll
                    for (int r = 0; r < 4; r++) {
                        int row = base + wv * 32 + nt * 16 + l16 * 4 + r;
                        float v = o[r] + b2v[qt];
                        v = fmaxf(v, 0.01f * v);
                        ob[(size_t)row * OUT + q] = __float2bfloat16(v);
                    }
                }
            } else {
                float s = 0.f;
#pragma unroll
                for (int r = 0; r < 4; r++) {
                    float v = o[r] + b2v[qt];
                    s += fmaxf(v, 0.01f * v);
                }
                if (q < OUT) {
                    int p = (base >> 2) + wv * 8 + nt * 4 + l16;
                    if (FINAL)
                        ((float*)outp)[(size_t)p * OUT + q] = s;
                    else
                        ((__hip_bfloat16*)outp)[(size_t)p * OUT + q] = __float2bfloat16(s);
                }
            }
        }
    }
}

extern "C" void kernel_launch(void* const* d_in, const int* in_sizes, int n_in,
                              void* d_out, int out_size, void* d_ws, size_t ws_size,
                              hipStream_t stream) {
    const float* node_msg = (const float*)d_in[0];
    const float* bonds = (const float*)d_in[1];
    const float* W1 = (const float*)d_in[2];
    const float* b1 = (const float*)d_in[3];
    const float* W2 = (const float*)d_in[4];
    const float* b2 = (const float*)d_in[5];
    float* out = (float*)d_out;

    char* ws = (char*)d_ws;
    __hip_bfloat16* bufA = (__hip_bfloat16*)ws;                      // 524288*40 bf16
    __hip_bfloat16* bufB = (__hip_bfloat16*)(ws + 41943040);         // 131072*40 bf16
    unsigned short* w1h = (unsigned short*)(ws + 52428800);          // 49152 B
    unsigned short* w1l = (unsigned short*)(ws + 52428800 + 49152);  // 49152 B
    unsigned int* w2f = (unsigned int*)(ws + 52428800 + 98304);      // 12288 B

    prep_w1<<<96, 256, 0, stream>>>(W1, w1h, w1l);
    prep_w2<<<1, 256, 0, stream>>>(W2, w2f);

    // d=4 (leaf): 524288 rows
    level_mlp<true, false><<<4096, 256, 0, stream>>>(
        node_msg + (size_t)175104 * ATOM, nullptr, nullptr, w1h, w1l, w2f, b1, b2, bufA);
    // d=3: 524288 edges -> 131072 parents
    level_mlp<false, false><<<4096, 256, 0, stream>>>(
        node_msg + (size_t)43008 * ATOM, bonds + (size_t)172032 * BOND, bufA,
        w1h, w1l, w2f, b1, b2, bufB);
    // d=2: 131072 edges -> 32768 parents
    level_mlp<false, false><<<1024, 256, 0, stream>>>(
        node_msg + (size_t)10240 * ATOM, bonds + (size_t)40960 * BOND, bufB,
        w1h, w1l, w2f, b1, b2, bufA);
    // d=1: 32768 edges -> 8192 parents
    level_mlp<false, false><<<256, 256, 0, stream>>>(
        node_msg + (size_t)2048 * ATOM, bonds + (size_t)8192 * BOND, bufA,
        w1h, w1l, w2f, b1, b2, bufB);
    // d=0: 8192 edges -> 2048 parents, final fp32 output
    level_mlp<false, true><<<64, 256, 0, stream>>>(
        node_msg, bonds, bufB, w1h, w1l, w2f, b1, b2, out);
}